// Round 4
// baseline (56.101 us; speedup 1.0000x reference)
//
#include <hip/hip_runtime.h>

typedef float v2f __attribute__((ext_vector_type(2)));

constexpr int IN_D = 18, W_HID = 10, N_HID = 19;
constexpr float SLOPE = 0.1f;

__device__ __forceinline__ v2f splat(float s) { v2f v; v[0] = s; v[1] = s; return v; }

__device__ __forceinline__ v2f lrelu2(v2f x) {
    // max(x, slope*x) == leaky_relu(x) for 0<slope<1 -> v_pk_mul_f32 + v_pk_max_f32
    return __builtin_elementwise_max(x, x * splat(SLOPE));
}

// 4 samples per thread, ROLLED hidden-layer loop (code must fit I$).
__global__ __launch_bounds__(256) void critic_fused_pk4r(
    const float* __restrict__ state, const float* __restrict__ action,
    const float* __restrict__ W0, const float* __restrict__ bias0,
    const float* __restrict__ Ws, const float* __restrict__ bs,
    const float* __restrict__ Wf, const float* __restrict__ bf,
    float* __restrict__ out, int B)
{
    const int t = blockIdx.x * blockDim.x + threadIdx.x;
    if (t * 4 >= B) return;

    // ---- load 4 state rows (192 B, 16B-aligned) as 12x float4 ----
    float Sf[48];
    {
        const float4* s4 = reinterpret_cast<const float4*>(state) + (size_t)t * 12;
        #pragma unroll
        for (int r = 0; r < 12; ++r) {
            float4 v = s4[r];
            Sf[4*r] = v.x; Sf[4*r+1] = v.y; Sf[4*r+2] = v.z; Sf[4*r+3] = v.w;
        }
    }
    // ---- load 4 action rows (96 B, 16B-aligned) as 6x float4 ----
    float Af[24];
    {
        const float4* a4 = reinterpret_cast<const float4*>(action) + (size_t)t * 6;
        #pragma unroll
        for (int r = 0; r < 6; ++r) {
            float4 v = a4[r];
            Af[4*r] = v.x; Af[4*r+1] = v.y; Af[4*r+2] = v.z; Af[4*r+3] = v.w;
        }
    }

    // pack inputs: xa = {s0,s1}, xb = {s2,s3}
    v2f xa[IN_D], xb[IN_D];
    #pragma unroll
    for (int k = 0; k < 12; ++k) {
        v2f a; a[0] = Sf[k];      a[1] = Sf[12 + k]; xa[k] = a;
        v2f b; b[0] = Sf[24 + k]; b[1] = Sf[36 + k]; xb[k] = b;
    }
    #pragma unroll
    for (int k = 0; k < 6; ++k) {
        v2f a; a[0] = Af[k];      a[1] = Af[6 + k];  xa[12 + k] = a;
        v2f b; b[0] = Af[12 + k]; b[1] = Af[18 + k]; xb[12 + k] = b;
    }

    // ---- layer 0: 18 -> 10 ----
    v2f ha[W_HID], hb[W_HID];
    #pragma unroll
    for (int j = 0; j < W_HID; ++j) {
        v2f aa = splat(bias0[j]);
        v2f ab = aa;
        #pragma unroll
        for (int k = 0; k < IN_D; ++k) {
            v2f w = splat(W0[j*IN_D + k]);
            aa = __builtin_elementwise_fma(xa[k], w, aa);
            ab = __builtin_elementwise_fma(xb[k], w, ab);
        }
        ha[j] = lrelu2(aa);
        hb[j] = lrelu2(ab);
    }

    // ---- 19 hidden layers: ROLLED so the body (~2 KB) stays I$-resident ----
    const float* __restrict__ W  = Ws;
    const float* __restrict__ bb = bs;
    #pragma unroll 1
    for (int l = 0; l < N_HID; ++l) {
        v2f na[W_HID], nb[W_HID];
        #pragma unroll
        for (int j = 0; j < W_HID; ++j) {
            v2f aa = splat(bb[j]);
            v2f ab = aa;
            #pragma unroll
            for (int k = 0; k < W_HID; ++k) {
                v2f w = splat(W[j*W_HID + k]);
                aa = __builtin_elementwise_fma(ha[k], w, aa);
                ab = __builtin_elementwise_fma(hb[k], w, ab);
            }
            na[j] = lrelu2(aa);
            nb[j] = lrelu2(ab);
        }
        #pragma unroll
        for (int j = 0; j < W_HID; ++j) { ha[j] = na[j]; hb[j] = nb[j]; }
        W  += W_HID * W_HID;
        bb += W_HID;
    }

    // ---- final layer: 10 -> 1 ----
    v2f aa = splat(bf[0]);
    v2f ab = aa;
    #pragma unroll
    for (int k = 0; k < W_HID; ++k) {
        v2f w = splat(Wf[k]);
        aa = __builtin_elementwise_fma(ha[k], w, aa);
        ab = __builtin_elementwise_fma(hb[k], w, ab);
    }
    aa = lrelu2(aa);
    ab = lrelu2(ab);

    float4 o; o.x = aa[0]; o.y = aa[1]; o.z = ab[0]; o.w = ab[1];
    reinterpret_cast<float4*>(out)[t] = o;   // 16B-aligned coalesced store
}

extern "C" void kernel_launch(void* const* d_in, const int* in_sizes, int n_in,
                              void* d_out, int out_size, void* d_ws, size_t ws_size,
                              hipStream_t stream) {
    const float* state  = (const float*)d_in[0];
    const float* action = (const float*)d_in[1];
    const float* W0     = (const float*)d_in[2];
    const float* b0     = (const float*)d_in[3];
    const float* Ws     = (const float*)d_in[4];
    const float* bs     = (const float*)d_in[5];
    const float* Wf     = (const float*)d_in[6];
    const float* bf     = (const float*)d_in[7];
    float* out = (float*)d_out;

    const int B = out_size;                  // [1, B] flat; B = 1048576 (div by 4)
    const int nthreads = B / 4;              // 4 samples per thread
    const int block = 256;
    const int grid = (nthreads + block - 1) / block;
    critic_fused_pk4r<<<grid, block, 0, stream>>>(state, action, W0, b0, Ws, bs, Wf, bf, out, B);
}

// Round 5
// 54.319 us; speedup vs baseline: 1.0328x; 1.0328x over previous
//
#include <hip/hip_runtime.h>

typedef float v2f __attribute__((ext_vector_type(2)));

constexpr int IN_D = 18, W_HID = 10, N_HID = 19;
constexpr float SLOPE = 0.1f;

__device__ __forceinline__ v2f splat(float s) { v2f v; v[0] = s; v[1] = s; return v; }

__device__ __forceinline__ v2f lrelu2(v2f x) {
    // max(x, slope*x) == leaky_relu(x) for 0<slope<1 -> v_pk_mul_f32 + v_pk_max_f32
    return __builtin_elementwise_max(x, x * splat(SLOPE));
}

// One 10->10 layer: in -> out, weights at W (100 floats), bias at bb (10 floats).
__device__ __forceinline__ void layer10(const v2f* __restrict__ in, v2f* __restrict__ outv,
                                        const float* __restrict__ W, const float* __restrict__ bb) {
    #pragma unroll
    for (int j = 0; j < W_HID; ++j) {
        v2f acc = splat(bb[j]);
        #pragma unroll
        for (int k = 0; k < W_HID; ++k)
            acc = __builtin_elementwise_fma(in[k], splat(W[j*W_HID + k]), acc);
        outv[j] = lrelu2(acc);
    }
}

// 2 samples per thread, rolled loop (I$-resident), 2 layers/iter ping-pong, 8 waves/SIMD.
__global__ __launch_bounds__(256, 8) void critic_pk2r(
    const float* __restrict__ state, const float* __restrict__ action,
    const float* __restrict__ W0, const float* __restrict__ bias0,
    const float* __restrict__ Ws, const float* __restrict__ bs,
    const float* __restrict__ Wf, const float* __restrict__ bf,
    float* __restrict__ out, int B)
{
    const int t = blockIdx.x * blockDim.x + threadIdx.x;
    if (t * 2 >= B) return;

    // ---- 2 state rows (96 B, 16B-aligned) as 6x float4 ----
    float Sf[24];
    {
        const float4* s4 = reinterpret_cast<const float4*>(state) + (size_t)t * 6;
        #pragma unroll
        for (int r = 0; r < 6; ++r) {
            float4 v = s4[r];
            Sf[4*r] = v.x; Sf[4*r+1] = v.y; Sf[4*r+2] = v.z; Sf[4*r+3] = v.w;
        }
    }
    // ---- 2 action rows (48 B, 16B-aligned) as 3x float4 ----
    float Af[12];
    {
        const float4* a4 = reinterpret_cast<const float4*>(action) + (size_t)t * 3;
        #pragma unroll
        for (int r = 0; r < 3; ++r) {
            float4 v = a4[r];
            Af[4*r] = v.x; Af[4*r+1] = v.y; Af[4*r+2] = v.z; Af[4*r+3] = v.w;
        }
    }

    // pack: slot0 = sample 2t, slot1 = sample 2t+1
    v2f x[IN_D];
    #pragma unroll
    for (int k = 0; k < 12; ++k) { v2f v; v[0] = Sf[k]; v[1] = Sf[12 + k]; x[k] = v; }
    #pragma unroll
    for (int k = 0; k < 6; ++k)  { v2f v; v[0] = Af[k]; v[1] = Af[6 + k];  x[12 + k] = v; }

    // ---- layer 0: 18 -> 10 ----
    v2f h[W_HID], g[W_HID];
    #pragma unroll
    for (int j = 0; j < W_HID; ++j) {
        v2f acc = splat(bias0[j]);
        #pragma unroll
        for (int k = 0; k < IN_D; ++k)
            acc = __builtin_elementwise_fma(x[k], splat(W0[j*IN_D + k]), acc);
        h[j] = lrelu2(acc);
    }

    // ---- hidden layers 0..17: 9 iterations x 2 layers, ping-pong h->g->h ----
    const float* __restrict__ W  = Ws;
    const float* __restrict__ bb = bs;
    #pragma unroll 1
    for (int it = 0; it < (N_HID - 1) / 2; ++it) {
        layer10(h, g, W,             bb);
        layer10(g, h, W + W_HID*W_HID, bb + W_HID);
        W  += 2 * W_HID * W_HID;
        bb += 2 * W_HID;
    }
    // ---- hidden layer 18 (last): h -> g ----
    layer10(h, g, W, bb);

    // ---- final layer: 10 -> 1 ----
    v2f acc = splat(bf[0]);
    #pragma unroll
    for (int k = 0; k < W_HID; ++k)
        acc = __builtin_elementwise_fma(g[k], splat(Wf[k]), acc);
    acc = lrelu2(acc);

    float2 o; o.x = acc[0]; o.y = acc[1];
    reinterpret_cast<float2*>(out)[t] = o;   // 8B-aligned coalesced store
}

extern "C" void kernel_launch(void* const* d_in, const int* in_sizes, int n_in,
                              void* d_out, int out_size, void* d_ws, size_t ws_size,
                              hipStream_t stream) {
    const float* state  = (const float*)d_in[0];
    const float* action = (const float*)d_in[1];
    const float* W0     = (const float*)d_in[2];
    const float* b0     = (const float*)d_in[3];
    const float* Ws     = (const float*)d_in[4];
    const float* bs     = (const float*)d_in[5];
    const float* Wf     = (const float*)d_in[6];
    const float* bf     = (const float*)d_in[7];
    float* out = (float*)d_out;

    const int B = out_size;                  // [1, B] flat; B = 1048576 (even)
    const int nthreads = B / 2;              // 2 samples per thread
    const int block = 256;
    const int grid = (nthreads + block - 1) / block;
    critic_pk2r<<<grid, block, 0, stream>>>(state, action, W0, b0, Ws, bs, Wf, bf, out, B);
}